// Round 2
// 2379.131 us; speedup vs baseline: 1.3910x; 1.3910x over previous
//
#include <hip/hip_runtime.h>
#include <hip/hip_bf16.h>

typedef __hip_bfloat16 bf16;
typedef __attribute__((ext_vector_type(8))) short short8;
typedef __attribute__((ext_vector_type(4))) float f32x4;

#define DEV __device__ __forceinline__

DEV float sig_(float x) { return 1.f / (1.f + __expf(-x)); }
DEV float tanh_(float x) {
  float a = fabsf(x);
  float e = __expf(-2.f * a);
  float t = (1.f - e) / (1.f + e);
  return copysignf(t, x);
}
DEV float b2f(unsigned short u) {
  union { unsigned int i; float f; } v; v.i = ((unsigned int)u) << 16; return v.f;
}
DEV unsigned short f2b(float f) {
  bf16 h = __float2bfloat16(f);
  return *reinterpret_cast<unsigned short*>(&h);
}

DEV void gl_lds16(const void* g, void* l) {
  __builtin_amdgcn_global_load_lds((const __attribute__((address_space(1))) void*)g,
                                   (__attribute__((address_space(3))) void*)l, 16, 0, 0);
}

// raw barrier with compile-time memory fences (no vmcnt(0) drain, unlike __syncthreads)
DEV void bar_() {
  asm volatile("" ::: "memory");
  __builtin_amdgcn_s_barrier();
  asm volatile("" ::: "memory");
}

enum { EPI_TANH_SPLIT = 0, EPI_LSTM = 1, EPI_PRE = 2, EPI_PREG = 3, EPI_OUT = 4 };

// ---------------- 128^2 m97-style engine (kept for small/one-off GEMMs) ----------------
template <int EPI>
__global__ __launch_bounds__(256, 2) void gemm_k(
    const bf16* __restrict__ A1, int lda1,
    const bf16* __restrict__ A2, int lda2, int kSplit,
    const bf16* __restrict__ Bw, int ldb, int K,
    const float* __restrict__ bias, const bf16* __restrict__ pgin,
    float* __restrict__ cbuf, bf16* __restrict__ hout,
    float* __restrict__ fout, int nStep)
{
  __shared__ __align__(128) char smem[32768];
  char* As = smem;
  char* Bs = smem + 16384;
  const int tid = threadIdx.x;
  const int lane = tid & 63;
  const int w = tid >> 6;
  const int kg = lane >> 4;
  const int l15 = lane & 15;
  const int quad = lane >> 4;
  const int bm = blockIdx.y * 128;
  const int bn = blockIdx.x * 128;
  const int wrow = w >> 1, wcol = w & 1;

  f32x4 acc[4][4];
#pragma unroll
  for (int i = 0; i < 4; i++)
#pragma unroll
    for (int j = 0; j < 4; j++) acc[i][j] = {0.f, 0.f, 0.f, 0.f};

  for (int k0 = 0; k0 < K; k0 += 64) {
    __syncthreads();
#pragma unroll
    for (int cc = 0; cc < 4; cc++) {
      const int c = w * 4 + cc;           // chunk id 0..15, wave-uniform
      const int mhi = c >> 1, ks = c & 1;
      const int gk = k0 + ks * 32 + kg * 8;
      {
        const int grow = bm + mhi * 16 + l15;
        const bf16* src = (gk < kSplit) ? (A1 + (size_t)grow * lda1 + gk)
                                        : (A2 + (size_t)grow * lda2 + (gk - kSplit));
        gl_lds16(src, As + c * 1024);
      }
      {
        const int grow = bn + mhi * 16 + l15;
        gl_lds16(Bw + (size_t)grow * ldb + gk, Bs + c * 1024);
      }
    }
    __syncthreads();
#pragma unroll
    for (int ks = 0; ks < 2; ks++) {
      short8 af[4], bfr[4];
#pragma unroll
      for (int i = 0; i < 4; i++) {
        af[i]  = *(const short8*)(As + ((wrow * 4 + i) * 2 + ks) * 1024 + lane * 16);
        bfr[i] = *(const short8*)(Bs + ((wcol * 4 + i) * 2 + ks) * 1024 + lane * 16);
      }
#pragma unroll
      for (int i = 0; i < 4; i++)
#pragma unroll
        for (int j = 0; j < 4; j++)
          acc[i][j] = __builtin_amdgcn_mfma_f32_16x16x32_bf16(af[i], bfr[j], acc[i][j], 0, 0, 0);
    }
  }

  const int row0 = bm + wrow * 64;
  const int col0 = bn + wcol * 64;   // multiple of 64
  __syncthreads();                    // smem reuse for staged epilogues

  if constexpr (EPI == EPI_LSTM) {
    // gate-permuted: wave's 4 nj tiles = gates i,f,g,o for j = (col0>>2)+l15
    const int j = (col0 >> 2) + l15;
    const int jj = wcol * 16 + l15;
    float* c_s = (float*)smem;                           // [128][32] f32
    unsigned short* h_s = (unsigned short*)(smem + 16384); // [128][32] bf16
    const ushort4* pg4 = (const ushort4*)pgin;
#pragma unroll
    for (int mi = 0; mi < 4; mi++) {
#pragma unroll
      for (int r = 0; r < 4; r++) {
        const int m = row0 + mi * 16 + quad * 4 + r;
        const int lr = wrow * 64 + mi * 16 + quad * 4 + r;
        float iv = acc[mi][0][r], fv = acc[mi][1][r], gv = acc[mi][2][r], ov = acc[mi][3][r];
        if (bias) {
          iv += bias[col0 + l15];
          fv += bias[col0 + 16 + l15];
          gv += bias[col0 + 32 + l15];
          ov += bias[col0 + 48 + l15];
        }
        if (pgin) {
          ushort4 q = pg4[(size_t)m * 1024 + j];
          iv += b2f(q.x); fv += b2f(q.y); gv += b2f(q.z); ov += b2f(q.w);
        }
        const size_t cidx = (size_t)m * 1024 + j;
        const float cold = cbuf[cidx];
        const float cn = sig_(fv) * cold + sig_(iv) * tanh_(gv);
        const float hv = sig_(ov) * tanh_(cn);
        c_s[lr * 32 + jj] = cn;
        h_s[lr * 32 + jj] = f2b(hv);
      }
    }
    __syncthreads();
    const int j0 = bn >> 2;
#pragma unroll
    for (int it = 0; it < 16; it++) {
      int idx = it * 256 + tid;
      int rr = idx >> 5, cc = idx & 31;
      cbuf[(size_t)(bm + rr) * 1024 + j0 + cc] = c_s[idx];   // 128B/row full lines
    }
    const unsigned int* h_s2 = (const unsigned int*)h_s;
    unsigned int* hg = (unsigned int*)hout;
#pragma unroll
    for (int it = 0; it < 8; it++) {
      int idx = it * 256 + tid;
      int rr = idx >> 4, cc = idx & 15;
      hg[(size_t)(bm + rr) * 512 + (j0 >> 1) + cc] = h_s2[idx]; // 64B/row
    }
  } else if constexpr (EPI == EPI_PREG) {
    // write bf16 gate-interleaved pre_gates: pg[((m*1024+j)*4)+gate]
    unsigned short* ps = (unsigned short*)smem;            // [128][32][4] bf16 = 32KB
#pragma unroll
    for (int mi = 0; mi < 4; mi++) {
#pragma unroll
      for (int r = 0; r < 4; r++) {
        const int lr = wrow * 64 + mi * 16 + quad * 4 + r;
#pragma unroll
        for (int nj = 0; nj < 4; nj++) {
          const int col = col0 + nj * 16 + l15;            // gate == nj (col0 % 64 == 0)
          float v = acc[mi][nj][r] + bias[col];
          ps[(lr * 32 + (wcol * 16 + l15)) * 4 + nj] = f2b(v);
        }
      }
    }
    __syncthreads();
    ushort4* pgo = (ushort4*)hout;
    const ushort4* ls4 = (const ushort4*)smem;
    const int j0 = bn >> 2;
#pragma unroll
    for (int it = 0; it < 16; it++) {
      int idx = it * 256 + tid;
      int rr = idx >> 5, cc = idx & 31;
      pgo[(size_t)(bm + rr) * 1024 + j0 + cc] = ls4[idx];  // 256B/row
    }
  } else if constexpr (EPI == EPI_OUT) {
    // staged fp32 out tile, scattered row mapping; two 64-row passes (32KB LDS)
    float* ls = (float*)smem;                              // [64][128] f32
#pragma unroll
    for (int p = 0; p < 2; p++) {
      if (p) __syncthreads();
#pragma unroll
      for (int mih = 0; mih < 2; mih++) {
        const int mi = 2 * p + mih;
#pragma unroll
        for (int r = 0; r < 4; r++) {
          const int slot = wrow * 32 + mih * 16 + quad * 4 + r;
#pragma unroll
          for (int nj = 0; nj < 4; nj++) {
            const int col = col0 + nj * 16 + l15;
            ls[slot * 128 + wcol * 64 + nj * 16 + l15] = acc[mi][nj][r] + bias[col];
          }
        }
      }
      __syncthreads();
      const float4* ls4 = (const float4*)smem;
      float4* og = (float4*)fout;
#pragma unroll
      for (int it = 0; it < 8; it++) {
        int idx = it * 256 + tid;
        int rr = idx >> 5, cc = idx & 31;
        int lrow = (rr >> 5) * 64 + p * 32 + (rr & 31);
        int mm = bm + lrow;
        int n_ = (nStep >= 0) ? nStep : (mm >> 12);
        int s_ = (mm >> 8) & 15, b_ = mm & 255;
        int orow = b_ * 256 + s_ * 16 + n_;
        og[(size_t)orow * 128 + (bn >> 2) + cc] = ls4[idx]; // 512B/row
      }
    }
  } else {
    // EPI_TANH_SPLIT / EPI_PRE — small one-time dispatches, unstaged
#pragma unroll
    for (int mi = 0; mi < 4; mi++) {
#pragma unroll
      for (int r = 0; r < 4; r++) {
        const int m = row0 + mi * 16 + quad * 4 + r;
#pragma unroll
        for (int nj = 0; nj < 4; nj++) {
          const int col = col0 + nj * 16 + l15;
          float v = acc[mi][nj][r] + bias[col];
          if constexpr (EPI == EPI_TANH_SPLIT) {
            v = tanh_(v);
            if (col < 1024) hout[(size_t)m * 1024 + col] = __float2bfloat16(v);
            else            fout[(size_t)m * 1024 + (col - 1024)] = v;
          } else if constexpr (EPI == EPI_PRE) {
            hout[(size_t)m * 2048 + col] = __float2bfloat16(v);
            if (col >= 1024) fout[(size_t)m * 1024 + (col - 1024)] = v;
          }
        }
      }
    }
  }
}

// ---------------- 256^2 8-wave pipelined engine (dec-LSTM steps) ----------------
// BM=BN=256, BK=64, 512 threads (8 waves = 2M x 4N, each owns 128x64 output).
// LDS 128 KiB: double-buffered A(32K)+B(32K) in fragment-order 1024B chunks
// (16 rows x 32 cols, lane*16) -> conflict-free ds_read_b128, linear
// global_load_lds dest (no swizzle needed).
// Schedule: 4 phases per K-tile, raw s_barrier (no vmcnt(0) drain), counted
// s_waitcnt vmcnt(4) once per tile (2 half-tiles x 2 loads stay in flight),
// setprio(1) around each 16-MFMA quadrant cluster.
// Stage ledger (tile v halves): B_h0(v)@(v-2,p2), A_h0(v)@(v-2,p3),
// B_h1(v)@(v-1,p0), A_h1(v)@(v-1,p1). Region last-reads: B halves @p1,
// A halves @p2 -> every stage lands >=1 barrier after the region's last read.
// vmcnt(4) before the p3-end barrier guarantees (per wave, then via barrier
// for all waves) that all of tile u+1 has landed before its first ds_read.
__global__ __launch_bounds__(512, 2) void gemm256_lstm(
    const bf16* __restrict__ A1, int lda1,
    const bf16* __restrict__ A2, int lda2, int kSplit,
    const bf16* __restrict__ Bw, int ldb, int K,
    const float* __restrict__ bias, const bf16* __restrict__ pgin,
    float* __restrict__ cbuf, bf16* __restrict__ hout)
{
  __shared__ __align__(1024) char smem[131072];
  const int tid = threadIdx.x;
  const int lane = tid & 63;
  const int w = tid >> 6;          // 0..7
  const int kg = lane >> 4;
  const int l15 = lane & 15;
  const int quad = lane >> 4;
  const int bm = blockIdx.y * 256;
  const int bn = blockIdx.x * 256;
  const int wr = w >> 2, wc = w & 3;
  const int wr8 = wr * 8, wc4 = wc * 4;
  const int nt = K >> 6;

  f32x4 acc[8][4];
#pragma unroll
  for (int i = 0; i < 8; i++)
#pragma unroll
    for (int j = 0; j < 4; j++) acc[i][j] = {0.f, 0.f, 0.f, 0.f};

  // stage one half-tile (16 chunks, 2 per wave) of tile vt; isB: operand, hi: half
  auto stage = [&](int isB, int hi, int vt) {
    if (vt >= nt) return;
    const int k0 = vt << 6;
    char* base = smem + (vt & 1) * 65536 + (isB ? 32768 : 0);
#pragma unroll
    for (int cc = 0; cc < 2; cc++) {
      const int c = hi * 16 + w * 2 + cc;
      const int mhi = c >> 1, ks = c & 1;
      const int gk = k0 + ks * 32 + kg * 8;
      const bf16* src;
      if (isB) {
        src = Bw + (size_t)(bn + mhi * 16 + l15) * ldb + gk;
      } else {
        const int grow = bm + mhi * 16 + l15;
        src = (gk < kSplit) ? (A1 + (size_t)grow * lda1 + gk)
                            : (A2 + (size_t)grow * lda2 + (gk - kSplit));
      }
      gl_lds16(src, base + c * 1024);
    }
  };

  // prologue: tile0 {B_h0,A_h0,B_h1,A_h1} + tile1 {B_h0,A_h0}
  stage(1, 0, 0); stage(0, 0, 0); stage(1, 1, 0); stage(0, 1, 0);
  stage(1, 0, 1); stage(0, 0, 1);
  if (nt > 1) { asm volatile("s_waitcnt vmcnt(4)" ::: "memory"); }
  else        { asm volatile("s_waitcnt vmcnt(0)" ::: "memory"); }
  bar_();

  for (int u = 0; u < nt; ++u) {
    char* Ab = smem + (u & 1) * 65536;
    char* Bb = Ab + 32768;
    short8 af[4][2], bfr[4][2];

    // ---- phase 0: read af[0..3],bfr[0..1]; stage B_h1(u+1); mfma q(0,0)
#pragma unroll
    for (int i = 0; i < 4; i++)
#pragma unroll
      for (int ks = 0; ks < 2; ks++)
        af[i][ks] = *(const short8*)(Ab + ((wr8 + i) * 2 + ks) * 1024 + lane * 16);
#pragma unroll
    for (int j = 0; j < 2; j++)
#pragma unroll
      for (int ks = 0; ks < 2; ks++)
        bfr[j][ks] = *(const short8*)(Bb + ((wc4 + j) * 2 + ks) * 1024 + lane * 16);
    stage(1, 1, u + 1);
    bar_();
    __builtin_amdgcn_s_setprio(1);
#pragma unroll
    for (int i = 0; i < 4; i++)
#pragma unroll
      for (int j = 0; j < 2; j++)
#pragma unroll
        for (int ks = 0; ks < 2; ks++)
          acc[i][j] = __builtin_amdgcn_mfma_f32_16x16x32_bf16(af[i][ks], bfr[j][ks], acc[i][j], 0, 0, 0);
    __builtin_amdgcn_s_setprio(0);
    bar_();

    // ---- phase 1: read bfr[2..3]; stage A_h1(u+1); mfma q(0,1)
#pragma unroll
    for (int j = 0; j < 2; j++)
#pragma unroll
      for (int ks = 0; ks < 2; ks++)
        bfr[2 + j][ks] = *(const short8*)(Bb + ((wc4 + 2 + j) * 2 + ks) * 1024 + lane * 16);
    stage(0, 1, u + 1);
    bar_();
    __builtin_amdgcn_s_setprio(1);
#pragma unroll
    for (int i = 0; i < 4; i++)
#pragma unroll
      for (int j = 0; j < 2; j++)
#pragma unroll
        for (int ks = 0; ks < 2; ks++)
          acc[i][2 + j] = __builtin_amdgcn_mfma_f32_16x16x32_bf16(af[i][ks], bfr[2 + j][ks], acc[i][2 + j], 0, 0, 0);
    __builtin_amdgcn_s_setprio(0);
    bar_();

    // ---- phase 2: read af[4..7] (reuse regs); stage B_h0(u+2); mfma q(1,0)
#pragma unroll
    for (int i = 0; i < 4; i++)
#pragma unroll
      for (int ks = 0; ks < 2; ks++)
        af[i][ks] = *(const short8*)(Ab + ((wr8 + 4 + i) * 2 + ks) * 1024 + lane * 16);
    stage(1, 0, u + 2);
    bar_();
    __builtin_amdgcn_s_setprio(1);
#pragma unroll
    for (int i = 0; i < 4; i++)
#pragma unroll
      for (int j = 0; j < 2; j++)
#pragma unroll
        for (int ks = 0; ks < 2; ks++)
          acc[4 + i][j] = __builtin_amdgcn_mfma_f32_16x16x32_bf16(af[i][ks], bfr[j][ks], acc[4 + i][j], 0, 0, 0);
    __builtin_amdgcn_s_setprio(0);
    bar_();

    // ---- phase 3: stage A_h0(u+2); mfma q(1,1); counted vmcnt; barrier
    stage(0, 0, u + 2);
    bar_();
    __builtin_amdgcn_s_setprio(1);
#pragma unroll
    for (int i = 0; i < 4; i++)
#pragma unroll
      for (int j = 0; j < 2; j++)
#pragma unroll
        for (int ks = 0; ks < 2; ks++)
          acc[4 + i][2 + j] = __builtin_amdgcn_mfma_f32_16x16x32_bf16(af[i][ks], bfr[2 + j][ks], acc[4 + i][2 + j], 0, 0, 0);
    __builtin_amdgcn_s_setprio(0);
    // keep tile u+2's p2/p3 stages (4 loads) in flight; drain fully at tail
    if (u + 2 < nt) { asm volatile("s_waitcnt vmcnt(4)" ::: "memory"); }
    else            { asm volatile("s_waitcnt vmcnt(0)" ::: "memory"); }
    bar_();
  }

  // ---------------- LSTM epilogue (gate-permuted, staged through LDS) ----------------
  __syncthreads();
  const int col0 = bn + wc * 64;            // multiple of 64
  const int j = (col0 >> 2) + l15;
  const int jj = wc * 16 + l15;             // 0..63
  float* c_s = (float*)smem;                               // [256][64] f32 = 64KB
  unsigned short* h_s = (unsigned short*)(smem + 65536);   // [256][64] bf16 = 32KB
  const ushort4* pg4 = (const ushort4*)pgin;
#pragma unroll
  for (int mi = 0; mi < 8; mi++) {
#pragma unroll
    for (int r = 0; r < 4; r++) {
      const int lr = wr * 128 + mi * 16 + quad * 4 + r;
      const int m = bm + lr;
      float iv = acc[mi][0][r], fv = acc[mi][1][r], gv = acc[mi][2][r], ov = acc[mi][3][r];
      if (bias) {
        iv += bias[col0 + l15];
        fv += bias[col0 + 16 + l15];
        gv += bias[col0 + 32 + l15];
        ov += bias[col0 + 48 + l15];
      }
      if (pgin) {
        ushort4 q = pg4[(size_t)m * 1024 + j];
        iv += b2f(q.x); fv += b2f(q.y); gv += b2f(q.z); ov += b2f(q.w);
      }
      const size_t cidx = (size_t)m * 1024 + j;
      const float cold = cbuf[cidx];
      const float cn = sig_(fv) * cold + sig_(iv) * tanh_(gv);
      const float hv = sig_(ov) * tanh_(cn);
      c_s[lr * 64 + jj] = cn;
      h_s[lr * 64 + jj] = f2b(hv);
    }
  }
  __syncthreads();
  const int j0 = bn >> 2;
  float4* cb4 = (float4*)cbuf;                 // row = 256 float4
  const float4* cs4 = (const float4*)c_s;
#pragma unroll
  for (int it = 0; it < 8; it++) {
    int idx = it * 512 + tid;                  // 0..4095
    int rr = idx >> 4, cc = idx & 15;
    cb4[(size_t)(bm + rr) * 256 + (j0 >> 2) + cc] = cs4[idx];   // 256B/row
  }
  uint2* hg = (uint2*)hout;                    // row = 256 uint2
  const uint2* hs2 = (const uint2*)h_s;
#pragma unroll
  for (int it = 0; it < 8; it++) {
    int idx = it * 512 + tid;
    int rr = idx >> 4, cc = idx & 15;
    hg[(size_t)(bm + rr) * 256 + (j0 >> 2) + cc] = hs2[idx];    // 128B/row
  }
}

// ---------------- setup kernels ----------------

__global__ void k_cvt(const float* __restrict__ s, bf16* __restrict__ d, int n) {
  int i = blockIdx.x * 256 + threadIdx.x;
  if (i < n) d[i] = __float2bfloat16(s[i]);
}

// gate-permute: oldr = k*1024 + j, j = q*16 + r  ->  newr = q*64 + k*16 + r
DEV int permr(int oldr) {
  int k = oldr >> 10, j = oldr & 1023;
  return ((j >> 4) << 6) + (k << 4) + (j & 15);
}

__global__ void k_permute_w(const float* __restrict__ src, int srcStride,
                            bf16* __restrict__ dst, int shift) {
  int idx = blockIdx.x * 256 + threadIdx.x;
  int c = idx & ((1 << shift) - 1);
  int oldr = idx >> shift;
  if (oldr >= 4096) return;
  dst[((size_t)permr(oldr) << shift) + c] = __float2bfloat16(src[(size_t)oldr * srcStride + c]);
}

__global__ void k_wcat(const float* __restrict__ Wih, const float* __restrict__ Whh,
                       bf16* __restrict__ dst) {
  int idx = blockIdx.x * 256 + threadIdx.x;   // 4096*1536
  if (idx >= 4096 * 1536) return;
  int c = idx % 1536;
  int oldr = idx / 1536;
  float v = (c < 512) ? Wih[(size_t)oldr * 2560 + 2048 + c]
                      : Whh[(size_t)oldr * 1024 + (c - 512)];
  dst[(size_t)permr(oldr) * 1536 + c] = __float2bfloat16(v);
}

__global__ void k_bias(const float* a, const float* b, const float* c, const float* d,
                       float* cb, float* db) {
  int oldr = blockIdx.x * 256 + threadIdx.x;
  if (oldr >= 4096) return;
  int nr = permr(oldr);
  cb[nr] = a[oldr] + b[oldr];
  db[nr] = c[oldr] + d[oldr];
}

// tok_bf[n][m=s*256+b][t] = (n==0) ? 0 : x[b, s*16 + n - 1, t]
__global__ void k_tok(const float* __restrict__ x, bf16* __restrict__ tok) {
  int idx = blockIdx.x * 256 + threadIdx.x;   // 33,554,432
  int t = idx & 511;
  int m = (idx >> 9) & 4095;
  int n = idx >> 21;
  int b = m & 255, s = m >> 8;
  float v = 0.f;
  if (n > 0) v = x[(size_t)(b * 256 + s * 16 + n - 1) * 512 + t];
  tok[idx] = __float2bfloat16(v);
}

// ---------------- host ----------------

extern "C" void kernel_launch(void* const* d_in, const int* in_sizes, int n_in,
                              void* d_out, int out_size, void* d_ws, size_t ws_size,
                              hipStream_t stream) {
  (void)in_sizes; (void)n_in; (void)out_size;
  const float* z        = (const float*)d_in[0];
  const float* x        = (const float*)d_in[1];
  const float* lin_in_w = (const float*)d_in[2];
  const float* lin_in_b = (const float*)d_in[3];
  const float* cond_Whh = (const float*)d_in[5];
  const float* cond_bih = (const float*)d_in[6];
  const float* cond_bhh = (const float*)d_in[7];
  const float* pre_w    = (const float*)d_in[8];
  const float* pre_b    = (const float*)d_in[9];
  const float* dec_Wih  = (const float*)d_in[10];
  const float* dec_Whh  = (const float*)d_in[11];
  const float* dec_bih  = (const float*)d_in[12];
  const float* dec_bhh  = (const float*)d_in[13];
  const float* out_w    = (const float*)d_in[14];
  const float* out_b    = (const float*)d_in[15];
  float* out = (float*)d_out;

  char* ws = (char*)d_ws;
  size_t off = 0;
  auto alloc = [&](size_t bytes) {
    char* p = ws + off;
    off += (bytes + 255) & ~(size_t)255;
    return p;
  };
  bf16*  z_bf       = (bf16*)alloc((size_t)131072 * 2);
  bf16*  lin_w_bf   = (bf16*)alloc((size_t)1048576 * 2);
  bf16*  condWhh_bf = (bf16*)alloc((size_t)4194304 * 2);
  bf16*  preW_bf    = (bf16*)alloc((size_t)2097152 * 2);
  bf16*  Wctx_bf    = (bf16*)alloc((size_t)8388608 * 2);
  bf16*  Wcat_bf    = (bf16*)alloc((size_t)4096 * 1536 * 2);
  bf16*  outW_bf    = (bf16*)alloc((size_t)524288 * 2);
  float* cbias_p    = (float*)alloc((size_t)4096 * 4);
  float* dbias_p    = (float*)alloc((size_t)4096 * 4);
  bf16*  tok_bf     = (bf16*)alloc((size_t)33554432 * 2);
  bf16*  h0_bf      = (bf16*)alloc((size_t)262144 * 2);
  float* c_cond     = (float*)alloc((size_t)262144 * 4);
  bf16*  cond_outs  = (bf16*)alloc((size_t)4194304 * 2);
  bf16*  dec_in_bf  = (bf16*)alloc((size_t)8388608 * 2);
  float* c_dec      = (float*)alloc((size_t)4194304 * 4);
  bf16*  pg_bf      = (bf16*)alloc((size_t)16777216 * 2);   // bf16 gate-interleaved
  // h slabs: 16 (batched out-GEMM) if ws allows, else 2 (ping-pong)
  const size_t slab = (size_t)4194304;
  bool big = (off + 16 * slab * 2) <= ws_size;
  bf16* h_all = (bf16*)alloc((big ? 16 : 2) * slab * 2);

  // setup / conversion
  k_cvt<<<512,   256, 0, stream>>>(z,        z_bf,     131072);
  k_cvt<<<4096,  256, 0, stream>>>(lin_in_w, lin_w_bf, 1048576);
  k_cvt<<<8192,  256, 0, stream>>>(pre_w,    preW_bf,  2097152);
  k_cvt<<<2048,  256, 0, stream>>>(out_w,    outW_bf,  524288);
  k_permute_w<<<16384, 256, 0, stream>>>(cond_Whh, 1024, condWhh_bf, 10);
  k_permute_w<<<32768, 256, 0, stream>>>(dec_Wih,  2560, Wctx_bf,    11);
  k_wcat<<<24576, 256, 0, stream>>>(dec_Wih, dec_Whh, Wcat_bf);
  k_bias<<<16, 256, 0, stream>>>(cond_bih, cond_bhh, dec_bih, dec_bhh, cbias_p, dbias_p);
  k_tok<<<131072, 256, 0, stream>>>(x, tok_bf);

  // 1) hc0 = tanh(z @ lin_in_w.T + b): M=256, N=2048, K=512
  gemm_k<EPI_TANH_SPLIT><<<dim3(16, 2), 256, 0, stream>>>(
      z_bf, 512, z_bf, 512, 512, lin_w_bf, 512, 512,
      lin_in_b, nullptr, nullptr, h0_bf, c_cond, 0);

  // 2) cond LSTM: 16 steps, M=256, N=4096 (gate-permuted), K=1024
  for (int s = 0; s < 16; s++) {
    const bf16* hs = (s == 0) ? h0_bf : (cond_outs + (size_t)(s - 1) * 262144);
    gemm_k<EPI_LSTM><<<dim3(32, 2), 256, 0, stream>>>(
        hs, 1024, hs, 1024, 1024, condWhh_bf, 1024, 1024,
        cbias_p, nullptr, c_cond, cond_outs + (size_t)s * 262144, nullptr, 0);
  }

  // 3) dec_in = cond_outs @ pre_w.T + pre_b: M=4096, N=2048, K=1024
  gemm_k<EPI_PRE><<<dim3(16, 32), 256, 0, stream>>>(
      cond_outs, 1024, cond_outs, 1024, 1024, preW_bf, 1024, 1024,
      pre_b, nullptr, nullptr, dec_in_bf, c_dec, 0);

  // 4) pre_gates (bf16, gate-interleaved) = dec_in @ W_ctx.T + dec_bias: M=4096, N=4096, K=2048
  gemm_k<EPI_PREG><<<dim3(32, 32), 256, 0, stream>>>(
      dec_in_bf, 2048, dec_in_bf, 2048, 2048, Wctx_bf, 2048, 2048,
      dbias_p, nullptr, nullptr, pg_bf, nullptr, 0);

  // 5) dec LSTM on the 256^2 pipelined engine (h kept per step when big) + out GEMM
  for (int n = 0; n < 16; n++) {
    bf16* hcur = h_all + (size_t)(big ? n : (n & 1)) * slab;
    const bf16* hprev = (n == 0) ? dec_in_bf
                                 : (h_all + (size_t)(big ? (n - 1) : ((n - 1) & 1)) * slab);
    const int ldprev = (n == 0) ? 2048 : 1024;
    gemm256_lstm<<<dim3(16, 16), 512, 0, stream>>>(
        tok_bf + (size_t)n * 2097152, 512, hprev, ldprev, 512,
        Wcat_bf, 1536, 1536,
        nullptr, pg_bf, c_dec, hcur);
    if (!big) {
      gemm_k<EPI_OUT><<<dim3(4, 32), 256, 0, stream>>>(
          hcur, 1024, hcur, 1024, 1024, outW_bf, 1024, 1024,
          out_b, nullptr, nullptr, nullptr, out, n);
    }
  }
  if (big) {
    // batched out GEMM over all 16 steps: M=65536, N=512, K=1024
    gemm_k<EPI_OUT><<<dim3(4, 512), 256, 0, stream>>>(
        h_all, 1024, h_all, 1024, 1024, outW_bf, 1024, 1024,
        out_b, nullptr, nullptr, nullptr, out, -1);
  }
}

// Round 3
// 2269.532 us; speedup vs baseline: 1.4582x; 1.0483x over previous
//
#include <hip/hip_runtime.h>
#include <hip/hip_bf16.h>

typedef __hip_bfloat16 bf16;
typedef __attribute__((ext_vector_type(8))) short short8;
typedef __attribute__((ext_vector_type(4))) float f32x4;

#define DEV __device__ __forceinline__

DEV float sig_(float x) { return 1.f / (1.f + __expf(-x)); }
DEV float tanh_(float x) {
  float a = fabsf(x);
  float e = __expf(-2.f * a);
  float t = (1.f - e) / (1.f + e);
  return copysignf(t, x);
}
DEV float b2f(unsigned short u) {
  union { unsigned int i; float f; } v; v.i = ((unsigned int)u) << 16; return v.f;
}
DEV unsigned short f2b(float f) {
  bf16 h = __float2bfloat16(f);
  return *reinterpret_cast<unsigned short*>(&h);
}

DEV void gl_lds16(const void* g, void* l) {
  __builtin_amdgcn_global_load_lds((const __attribute__((address_space(1))) void*)g,
                                   (__attribute__((address_space(3))) void*)l, 16, 0, 0);
}

// raw barrier with compile-time memory fences (no vmcnt(0) drain, unlike __syncthreads)
DEV void bar_() {
  asm volatile("" ::: "memory");
  __builtin_amdgcn_s_barrier();
  asm volatile("" ::: "memory");
}

enum { EPI_TANH_SPLIT = 0, EPI_LSTM = 1, EPI_PRE = 2, EPI_PREG = 3, EPI_OUT = 4 };

// ---------------- 128^2 m97-style engine (small/one-off GEMMs) ----------------
template <int EPI>
__global__ __launch_bounds__(256, 2) void gemm_k(
    const bf16* __restrict__ A1, int lda1,
    const bf16* __restrict__ A2, int lda2, int kSplit,
    const bf16* __restrict__ Bw, int ldb, int K,
    const float* __restrict__ bias, const bf16* __restrict__ pgin,
    float* __restrict__ cbuf, bf16* __restrict__ hout,
    float* __restrict__ fout, int nStep)
{
  __shared__ __align__(128) char smem[32768];
  char* As = smem;
  char* Bs = smem + 16384;
  const int tid = threadIdx.x;
  const int lane = tid & 63;
  const int w = tid >> 6;
  const int kg = lane >> 4;
  const int l15 = lane & 15;
  const int quad = lane >> 4;
  const int bm = blockIdx.y * 128;
  const int bn = blockIdx.x * 128;
  const int wrow = w >> 1, wcol = w & 1;

  f32x4 acc[4][4];
#pragma unroll
  for (int i = 0; i < 4; i++)
#pragma unroll
    for (int j = 0; j < 4; j++) acc[i][j] = {0.f, 0.f, 0.f, 0.f};

  for (int k0 = 0; k0 < K; k0 += 64) {
    __syncthreads();
#pragma unroll
    for (int cc = 0; cc < 4; cc++) {
      const int c = w * 4 + cc;           // chunk id 0..15, wave-uniform
      const int mhi = c >> 1, ks = c & 1;
      const int gk = k0 + ks * 32 + kg * 8;
      {
        const int grow = bm + mhi * 16 + l15;
        const bf16* src = (gk < kSplit) ? (A1 + (size_t)grow * lda1 + gk)
                                        : (A2 + (size_t)grow * lda2 + (gk - kSplit));
        gl_lds16(src, As + c * 1024);
      }
      {
        const int grow = bn + mhi * 16 + l15;
        gl_lds16(Bw + (size_t)grow * ldb + gk, Bs + c * 1024);
      }
    }
    __syncthreads();
#pragma unroll
    for (int ks = 0; ks < 2; ks++) {
      short8 af[4], bfr[4];
#pragma unroll
      for (int i = 0; i < 4; i++) {
        af[i]  = *(const short8*)(As + ((wrow * 4 + i) * 2 + ks) * 1024 + lane * 16);
        bfr[i] = *(const short8*)(Bs + ((wcol * 4 + i) * 2 + ks) * 1024 + lane * 16);
      }
#pragma unroll
      for (int i = 0; i < 4; i++)
#pragma unroll
        for (int j = 0; j < 4; j++)
          acc[i][j] = __builtin_amdgcn_mfma_f32_16x16x32_bf16(af[i], bfr[j], acc[i][j], 0, 0, 0);
    }
  }

  const int row0 = bm + wrow * 64;
  const int col0 = bn + wcol * 64;   // multiple of 64
  __syncthreads();                    // smem reuse for staged epilogues

  if constexpr (EPI == EPI_LSTM) {
    // gate-permuted: wave's 4 nj tiles = gates i,f,g,o for j = (col0>>2)+l15
    const int j = (col0 >> 2) + l15;
    const int jj = wcol * 16 + l15;
    float* c_s = (float*)smem;                           // [128][32] f32
    unsigned short* h_s = (unsigned short*)(smem + 16384); // [128][32] bf16
    const ushort4* pg4 = (const ushort4*)pgin;
#pragma unroll
    for (int mi = 0; mi < 4; mi++) {
#pragma unroll
      for (int r = 0; r < 4; r++) {
        const int m = row0 + mi * 16 + quad * 4 + r;
        const int lr = wrow * 64 + mi * 16 + quad * 4 + r;
        float iv = acc[mi][0][r], fv = acc[mi][1][r], gv = acc[mi][2][r], ov = acc[mi][3][r];
        if (bias) {
          iv += bias[col0 + l15];
          fv += bias[col0 + 16 + l15];
          gv += bias[col0 + 32 + l15];
          ov += bias[col0 + 48 + l15];
        }
        if (pgin) {
          ushort4 q = pg4[(size_t)m * 1024 + j];
          iv += b2f(q.x); fv += b2f(q.y); gv += b2f(q.z); ov += b2f(q.w);
        }
        const size_t cidx = (size_t)m * 1024 + j;
        const float cold = cbuf[cidx];
        const float cn = sig_(fv) * cold + sig_(iv) * tanh_(gv);
        const float hv = sig_(ov) * tanh_(cn);
        c_s[lr * 32 + jj] = cn;
        h_s[lr * 32 + jj] = f2b(hv);
      }
    }
    __syncthreads();
    const int j0 = bn >> 2;
#pragma unroll
    for (int it = 0; it < 16; it++) {
      int idx = it * 256 + tid;
      int rr = idx >> 5, cc = idx & 31;
      cbuf[(size_t)(bm + rr) * 1024 + j0 + cc] = c_s[idx];   // 128B/row full lines
    }
    const unsigned int* h_s2 = (const unsigned int*)h_s;
    unsigned int* hg = (unsigned int*)hout;
#pragma unroll
    for (int it = 0; it < 8; it++) {
      int idx = it * 256 + tid;
      int rr = idx >> 4, cc = idx & 15;
      hg[(size_t)(bm + rr) * 512 + (j0 >> 1) + cc] = h_s2[idx]; // 64B/row
    }
  } else {
    // EPI_TANH_SPLIT / EPI_PRE — small one-time dispatches, unstaged
#pragma unroll
    for (int mi = 0; mi < 4; mi++) {
#pragma unroll
      for (int r = 0; r < 4; r++) {
        const int m = row0 + mi * 16 + quad * 4 + r;
#pragma unroll
        for (int nj = 0; nj < 4; nj++) {
          const int col = col0 + nj * 16 + l15;
          float v = acc[mi][nj][r] + bias[col];
          if constexpr (EPI == EPI_TANH_SPLIT) {
            v = tanh_(v);
            if (col < 1024) hout[(size_t)m * 1024 + col] = __float2bfloat16(v);
            else            fout[(size_t)m * 1024 + (col - 1024)] = v;
          } else if constexpr (EPI == EPI_PRE) {
            hout[(size_t)m * 2048 + col] = __float2bfloat16(v);
            if (col >= 1024) fout[(size_t)m * 1024 + (col - 1024)] = v;
          }
        }
      }
    }
  }
}

// ---------------- 256^2 8-wave pipelined engine ----------------
// BM=BN=256, BK=64, 512 threads (8 waves = 2M x 4N, each owns 128x64 output).
// LDS 128 KiB: double-buffered A(32K)+B(32K) in fragment-order 1024B chunks
// (16 rows x 32 cols, lane*16) -> conflict-free ds_read_b128, linear
// global_load_lds dest. 4 phases per K-tile, raw s_barrier, counted vmcnt(4)
// once per tile (tile u+2's h0 stages stay in flight), setprio(1) around each
// 16-MFMA quadrant cluster. Stage ledger verified: every stage lands >=1
// barrier after its region's last ds_read; vmcnt(4)+barrier at p3 guarantees
// tile u+1 fully landed before its first ds_read.
// Epilogues (LSTM / PREG / OUT) stage through the same 128KB LDS and write
// full-line coalesced rows.
template <int EPI>
__global__ __launch_bounds__(512, 2) void gemm256(
    const bf16* __restrict__ A1, int lda1,
    const bf16* __restrict__ A2, int lda2, int kSplit,
    const bf16* __restrict__ Bw, int ldb, int K,
    const float* __restrict__ bias, const bf16* __restrict__ pgin,
    float* __restrict__ cbuf, bf16* __restrict__ hout,
    float* __restrict__ fout, int nStep)
{
  __shared__ __align__(1024) char smem[131072];
  const int tid = threadIdx.x;
  const int lane = tid & 63;
  const int w = tid >> 6;          // 0..7
  const int kg = lane >> 4;
  const int l15 = lane & 15;
  const int quad = lane >> 4;
  const int bm = blockIdx.y * 256;
  const int bn = blockIdx.x * 256;
  const int wr = w >> 2, wc = w & 3;
  const int wr8 = wr * 8, wc4 = wc * 4;
  const int nt = K >> 6;

  f32x4 acc[8][4];
#pragma unroll
  for (int i = 0; i < 8; i++)
#pragma unroll
    for (int j = 0; j < 4; j++) acc[i][j] = {0.f, 0.f, 0.f, 0.f};

  // stage one half-tile (16 chunks, 2 per wave) of tile vt; isB: operand, hi: half
  auto stage = [&](int isB, int hi, int vt) {
    if (vt >= nt) return;
    const int k0 = vt << 6;
    char* base = smem + (vt & 1) * 65536 + (isB ? 32768 : 0);
#pragma unroll
    for (int cc = 0; cc < 2; cc++) {
      const int c = hi * 16 + w * 2 + cc;
      const int mhi = c >> 1, ks = c & 1;
      const int gk = k0 + ks * 32 + kg * 8;
      const bf16* src;
      if (isB) {
        src = Bw + (size_t)(bn + mhi * 16 + l15) * ldb + gk;
      } else {
        const int grow = bm + mhi * 16 + l15;
        src = (gk < kSplit) ? (A1 + (size_t)grow * lda1 + gk)
                            : (A2 + (size_t)grow * lda2 + (gk - kSplit));
      }
      gl_lds16(src, base + c * 1024);
    }
  };

  // prologue: tile0 {B_h0,A_h0,B_h1,A_h1} + tile1 {B_h0,A_h0}
  stage(1, 0, 0); stage(0, 0, 0); stage(1, 1, 0); stage(0, 1, 0);
  stage(1, 0, 1); stage(0, 0, 1);
  if (nt > 1) { asm volatile("s_waitcnt vmcnt(4)" ::: "memory"); }
  else        { asm volatile("s_waitcnt vmcnt(0)" ::: "memory"); }
  bar_();

  for (int u = 0; u < nt; ++u) {
    char* Ab = smem + (u & 1) * 65536;
    char* Bb = Ab + 32768;
    short8 af[4][2], bfr[4][2];

    // ---- phase 0: read af[0..3],bfr[0..1]; stage B_h1(u+1); mfma q(0,0)
#pragma unroll
    for (int i = 0; i < 4; i++)
#pragma unroll
      for (int ks = 0; ks < 2; ks++)
        af[i][ks] = *(const short8*)(Ab + ((wr8 + i) * 2 + ks) * 1024 + lane * 16);
#pragma unroll
    for (int j = 0; j < 2; j++)
#pragma unroll
      for (int ks = 0; ks < 2; ks++)
        bfr[j][ks] = *(const short8*)(Bb + ((wc4 + j) * 2 + ks) * 1024 + lane * 16);
    stage(1, 1, u + 1);
    bar_();
    __builtin_amdgcn_s_setprio(1);
#pragma unroll
    for (int i = 0; i < 4; i++)
#pragma unroll
      for (int j = 0; j < 2; j++)
#pragma unroll
        for (int ks = 0; ks < 2; ks++)
          acc[i][j] = __builtin_amdgcn_mfma_f32_16x16x32_bf16(af[i][ks], bfr[j][ks], acc[i][j], 0, 0, 0);
    __builtin_amdgcn_s_setprio(0);
    bar_();

    // ---- phase 1: read bfr[2..3]; stage A_h1(u+1); mfma q(0,1)
#pragma unroll
    for (int j = 0; j < 2; j++)
#pragma unroll
      for (int ks = 0; ks < 2; ks++)
        bfr[2 + j][ks] = *(const short8*)(Bb + ((wc4 + 2 + j) * 2 + ks) * 1024 + lane * 16);
    stage(0, 1, u + 1);
    bar_();
    __builtin_amdgcn_s_setprio(1);
#pragma unroll
    for (int i = 0; i < 4; i++)
#pragma unroll
      for (int j = 0; j < 2; j++)
#pragma unroll
        for (int ks = 0; ks < 2; ks++)
          acc[i][2 + j] = __builtin_amdgcn_mfma_f32_16x16x32_bf16(af[i][ks], bfr[2 + j][ks], acc[i][2 + j], 0, 0, 0);
    __builtin_amdgcn_s_setprio(0);
    bar_();

    // ---- phase 2: read af[4..7] (reuse regs); stage B_h0(u+2); mfma q(1,0)
#pragma unroll
    for (int i = 0; i < 4; i++)
#pragma unroll
      for (int ks = 0; ks < 2; ks++)
        af[i][ks] = *(const short8*)(Ab + ((wr8 + 4 + i) * 2 + ks) * 1024 + lane * 16);
    stage(1, 0, u + 2);
    bar_();
    __builtin_amdgcn_s_setprio(1);
#pragma unroll
    for (int i = 0; i < 4; i++)
#pragma unroll
      for (int j = 0; j < 2; j++)
#pragma unroll
        for (int ks = 0; ks < 2; ks++)
          acc[4 + i][j] = __builtin_amdgcn_mfma_f32_16x16x32_bf16(af[i][ks], bfr[j][ks], acc[4 + i][j], 0, 0, 0);
    __builtin_amdgcn_s_setprio(0);
    bar_();

    // ---- phase 3: stage A_h0(u+2); mfma q(1,1); counted vmcnt; barrier
    stage(0, 0, u + 2);
    bar_();
    __builtin_amdgcn_s_setprio(1);
#pragma unroll
    for (int i = 0; i < 4; i++)
#pragma unroll
      for (int j = 0; j < 2; j++)
#pragma unroll
        for (int ks = 0; ks < 2; ks++)
          acc[4 + i][2 + j] = __builtin_amdgcn_mfma_f32_16x16x32_bf16(af[i][ks], bfr[2 + j][ks], acc[4 + i][2 + j], 0, 0, 0);
    __builtin_amdgcn_s_setprio(0);
    // keep tile u+2's p2/p3 stages (4 loads) in flight; drain fully at tail
    if (u + 2 < nt) { asm volatile("s_waitcnt vmcnt(4)" ::: "memory"); }
    else            { asm volatile("s_waitcnt vmcnt(0)" ::: "memory"); }
    bar_();
  }

  // ---------------- epilogues (staged through the 128KB LDS) ----------------
  __syncthreads();
  const int col0 = bn + wc * 64;            // multiple of 64

  if constexpr (EPI == EPI_LSTM) {
    const int j = (col0 >> 2) + l15;
    const int jj = wc * 16 + l15;             // 0..63
    float* c_s = (float*)smem;                               // [256][64] f32 = 64KB
    unsigned short* h_s = (unsigned short*)(smem + 65536);   // [256][64] bf16 = 32KB
    const ushort4* pg4 = (const ushort4*)pgin;
#pragma unroll
    for (int mi = 0; mi < 8; mi++) {
#pragma unroll
      for (int r = 0; r < 4; r++) {
        const int lr = wr * 128 + mi * 16 + quad * 4 + r;
        const int m = bm + lr;
        float iv = acc[mi][0][r], fv = acc[mi][1][r], gv = acc[mi][2][r], ov = acc[mi][3][r];
        if (bias) {
          iv += bias[col0 + l15];
          fv += bias[col0 + 16 + l15];
          gv += bias[col0 + 32 + l15];
          ov += bias[col0 + 48 + l15];
        }
        if (pgin) {
          ushort4 q = pg4[(size_t)m * 1024 + j];
          iv += b2f(q.x); fv += b2f(q.y); gv += b2f(q.z); ov += b2f(q.w);
        }
        const size_t cidx = (size_t)m * 1024 + j;
        const float cold = cbuf[cidx];
        const float cn = sig_(fv) * cold + sig_(iv) * tanh_(gv);
        const float hv = sig_(ov) * tanh_(cn);
        c_s[lr * 64 + jj] = cn;
        h_s[lr * 64 + jj] = f2b(hv);
      }
    }
    __syncthreads();
    const int j0 = bn >> 2;
    float4* cb4 = (float4*)cbuf;                 // row = 256 float4
    const float4* cs4 = (const float4*)c_s;
#pragma unroll
    for (int it = 0; it < 8; it++) {
      int idx = it * 512 + tid;                  // 0..4095
      int rr = idx >> 4, cc = idx & 15;
      cb4[(size_t)(bm + rr) * 256 + (j0 >> 2) + cc] = cs4[idx];   // 256B/row
    }
    uint2* hg = (uint2*)hout;                    // row = 256 uint2
    const uint2* hs2 = (const uint2*)h_s;
#pragma unroll
    for (int it = 0; it < 8; it++) {
      int idx = it * 512 + tid;
      int rr = idx >> 4, cc = idx & 15;
      hg[(size_t)(bm + rr) * 256 + (j0 >> 2) + cc] = hs2[idx];    // 128B/row
    }
  } else if constexpr (EPI == EPI_PREG) {
    // bf16 gate-interleaved pre_gates: pg[((m*1024+j)*4)+gate]; gate == nj
    ushort4* ps = (ushort4*)smem;                 // [256][64] ushort4 = 128KB
    const int jj = wc * 16 + l15;                 // 0..63
#pragma unroll
    for (int mi = 0; mi < 8; mi++) {
#pragma unroll
      for (int r = 0; r < 4; r++) {
        const int lr = wr * 128 + mi * 16 + quad * 4 + r;
        ushort4 q;
        q.x = f2b(acc[mi][0][r] + bias[col0 + l15]);
        q.y = f2b(acc[mi][1][r] + bias[col0 + 16 + l15]);
        q.z = f2b(acc[mi][2][r] + bias[col0 + 32 + l15]);
        q.w = f2b(acc[mi][3][r] + bias[col0 + 48 + l15]);
        ps[lr * 64 + jj] = q;
      }
    }
    __syncthreads();
    ushort4* pgo = (ushort4*)hout;
    const ushort4* ls4 = (const ushort4*)smem;
    const int j0 = bn >> 2;
#pragma unroll
    for (int it = 0; it < 32; it++) {
      int idx = it * 512 + tid;                   // 0..16383
      int rr = idx >> 6, cc = idx & 63;
      pgo[(size_t)(bm + rr) * 1024 + j0 + cc] = ls4[idx];  // 512B/row
    }
  } else if constexpr (EPI == EPI_OUT) {
    // staged fp32 out tile, scattered row mapping; two 128-row passes (128KB LDS)
    float* ls = (float*)smem;                     // [128][256] f32
#pragma unroll
    for (int p = 0; p < 2; p++) {
      if (p) __syncthreads();
#pragma unroll
      for (int mih = 0; mih < 4; mih++) {
        const int mi = 4 * p + mih;
#pragma unroll
        for (int r = 0; r < 4; r++) {
          const int slot = wr * 64 + mih * 16 + quad * 4 + r;
#pragma unroll
          for (int nj = 0; nj < 4; nj++) {
            const int col = col0 + nj * 16 + l15;
            ls[slot * 256 + wc * 64 + nj * 16 + l15] = acc[mi][nj][r] + bias[col];
          }
        }
      }
      __syncthreads();
      const float4* ls4 = (const float4*)smem;
      float4* og = (float4*)fout;
#pragma unroll
      for (int it = 0; it < 16; it++) {
        int idx = it * 512 + tid;                 // 0..8191
        int rr = idx >> 6, cc = idx & 63;
        int lrow = (rr >> 6) * 128 + p * 64 + (rr & 63);
        int mm = bm + lrow;
        int n_ = (nStep >= 0) ? nStep : (mm >> 12);
        int s_ = (mm >> 8) & 15, b_ = mm & 255;
        int orow = b_ * 256 + s_ * 16 + n_;
        og[(size_t)orow * 128 + (bn >> 2) + cc] = ls4[idx]; // 1KB/row
      }
    }
  }
}

// ---------------- setup kernels ----------------

__global__ void k_cvt(const float* __restrict__ s, bf16* __restrict__ d, int n) {
  int i = blockIdx.x * 256 + threadIdx.x;
  if (i < n) d[i] = __float2bfloat16(s[i]);
}

// gate-permute: oldr = k*1024 + j, j = q*16 + r  ->  newr = q*64 + k*16 + r
DEV int permr(int oldr) {
  int k = oldr >> 10, j = oldr & 1023;
  return ((j >> 4) << 6) + (k << 4) + (j & 15);
}

__global__ void k_permute_w(const float* __restrict__ src, int srcStride,
                            bf16* __restrict__ dst, int shift) {
  int idx = blockIdx.x * 256 + threadIdx.x;
  int c = idx & ((1 << shift) - 1);
  int oldr = idx >> shift;
  if (oldr >= 4096) return;
  dst[((size_t)permr(oldr) << shift) + c] = __float2bfloat16(src[(size_t)oldr * srcStride + c]);
}

__global__ void k_wcat(const float* __restrict__ Wih, const float* __restrict__ Whh,
                       bf16* __restrict__ dst) {
  int idx = blockIdx.x * 256 + threadIdx.x;   // 4096*1536
  if (idx >= 4096 * 1536) return;
  int c = idx % 1536;
  int oldr = idx / 1536;
  float v = (c < 512) ? Wih[(size_t)oldr * 2560 + 2048 + c]
                      : Whh[(size_t)oldr * 1024 + (c - 512)];
  dst[(size_t)permr(oldr) * 1536 + c] = __float2bfloat16(v);
}

__global__ void k_bias(const float* a, const float* b, const float* c, const float* d,
                       float* cb, float* db) {
  int oldr = blockIdx.x * 256 + threadIdx.x;
  if (oldr >= 4096) return;
  int nr = permr(oldr);
  cb[nr] = a[oldr] + b[oldr];
  db[nr] = c[oldr] + d[oldr];
}

// tok_bf[n][m=s*256+b][t] = (n==0) ? 0 : x[b, s*16 + n - 1, t]
__global__ void k_tok(const float* __restrict__ x, bf16* __restrict__ tok) {
  int idx = blockIdx.x * 256 + threadIdx.x;   // 33,554,432
  int t = idx & 511;
  int m = (idx >> 9) & 4095;
  int n = idx >> 21;
  int b = m & 255, s = m >> 8;
  float v = 0.f;
  if (n > 0) v = x[(size_t)(b * 256 + s * 16 + n - 1) * 512 + t];
  tok[idx] = __float2bfloat16(v);
}

// ---------------- host ----------------

extern "C" void kernel_launch(void* const* d_in, const int* in_sizes, int n_in,
                              void* d_out, int out_size, void* d_ws, size_t ws_size,
                              hipStream_t stream) {
  (void)in_sizes; (void)n_in; (void)out_size;
  const float* z        = (const float*)d_in[0];
  const float* x        = (const float*)d_in[1];
  const float* lin_in_w = (const float*)d_in[2];
  const float* lin_in_b = (const float*)d_in[3];
  const float* cond_Whh = (const float*)d_in[5];
  const float* cond_bih = (const float*)d_in[6];
  const float* cond_bhh = (const float*)d_in[7];
  const float* pre_w    = (const float*)d_in[8];
  const float* pre_b    = (const float*)d_in[9];
  const float* dec_Wih  = (const float*)d_in[10];
  const float* dec_Whh  = (const float*)d_in[11];
  const float* dec_bih  = (const float*)d_in[12];
  const float* dec_bhh  = (const float*)d_in[13];
  const float* out_w    = (const float*)d_in[14];
  const float* out_b    = (const float*)d_in[15];
  float* out = (float*)d_out;

  char* ws = (char*)d_ws;
  size_t off = 0;
  auto alloc = [&](size_t bytes) {
    char* p = ws + off;
    off += (bytes + 255) & ~(size_t)255;
    return p;
  };
  bf16*  z_bf       = (bf16*)alloc((size_t)131072 * 2);
  bf16*  lin_w_bf   = (bf16*)alloc((size_t)1048576 * 2);
  bf16*  condWhh_bf = (bf16*)alloc((size_t)4194304 * 2);
  bf16*  preW_bf    = (bf16*)alloc((size_t)2097152 * 2);
  bf16*  Wctx_bf    = (bf16*)alloc((size_t)8388608 * 2);
  bf16*  Wcat_bf    = (bf16*)alloc((size_t)4096 * 1536 * 2);
  bf16*  outW_bf    = (bf16*)alloc((size_t)524288 * 2);
  float* cbias_p    = (float*)alloc((size_t)4096 * 4);
  float* dbias_p    = (float*)alloc((size_t)4096 * 4);
  bf16*  tok_bf     = (bf16*)alloc((size_t)33554432 * 2);
  bf16*  h0_bf      = (bf16*)alloc((size_t)262144 * 2);
  float* c_cond     = (float*)alloc((size_t)262144 * 4);
  bf16*  cond_outs  = (bf16*)alloc((size_t)4194304 * 2);
  bf16*  dec_in_bf  = (bf16*)alloc((size_t)8388608 * 2);
  float* c_dec      = (float*)alloc((size_t)4194304 * 4);
  bf16*  pg_bf      = (bf16*)alloc((size_t)16777216 * 2);   // bf16 gate-interleaved
  // h slabs: 16 (batched out-GEMM) if ws allows, else 2 (ping-pong)
  const size_t slab = (size_t)4194304;
  bool big = (off + 16 * slab * 2) <= ws_size;
  bf16* h_all = (bf16*)alloc((big ? 16 : 2) * slab * 2);

  // setup / conversion
  k_cvt<<<512,   256, 0, stream>>>(z,        z_bf,     131072);
  k_cvt<<<4096,  256, 0, stream>>>(lin_in_w, lin_w_bf, 1048576);
  k_cvt<<<8192,  256, 0, stream>>>(pre_w,    preW_bf,  2097152);
  k_cvt<<<2048,  256, 0, stream>>>(out_w,    outW_bf,  524288);
  k_permute_w<<<16384, 256, 0, stream>>>(cond_Whh, 1024, condWhh_bf, 10);
  k_permute_w<<<32768, 256, 0, stream>>>(dec_Wih,  2560, Wctx_bf,    11);
  k_wcat<<<24576, 256, 0, stream>>>(dec_Wih, dec_Whh, Wcat_bf);
  k_bias<<<16, 256, 0, stream>>>(cond_bih, cond_bhh, dec_bih, dec_bhh, cbias_p, dbias_p);
  k_tok<<<131072, 256, 0, stream>>>(x, tok_bf);

  // 1) hc0 = tanh(z @ lin_in_w.T + b): M=256, N=2048, K=512
  gemm_k<EPI_TANH_SPLIT><<<dim3(16, 2), 256, 0, stream>>>(
      z_bf, 512, z_bf, 512, 512, lin_w_bf, 512, 512,
      lin_in_b, nullptr, nullptr, h0_bf, c_cond, 0);

  // 2) cond LSTM: 16 steps, M=256, N=4096 (gate-permuted), K=1024
  for (int s = 0; s < 16; s++) {
    const bf16* hs = (s == 0) ? h0_bf : (cond_outs + (size_t)(s - 1) * 262144);
    gemm_k<EPI_LSTM><<<dim3(32, 2), 256, 0, stream>>>(
        hs, 1024, hs, 1024, 1024, condWhh_bf, 1024, 1024,
        cbias_p, nullptr, c_cond, cond_outs + (size_t)s * 262144, nullptr, 0);
  }

  // 3) dec_in = cond_outs @ pre_w.T + pre_b: M=4096, N=2048, K=1024
  gemm_k<EPI_PRE><<<dim3(16, 32), 256, 0, stream>>>(
      cond_outs, 1024, cond_outs, 1024, 1024, preW_bf, 1024, 1024,
      pre_b, nullptr, nullptr, dec_in_bf, c_dec, 0);

  // 4) pre_gates (bf16, gate-interleaved) = dec_in @ W_ctx.T + dec_bias
  //    M=4096, N=4096, K=2048 on the 256^2 engine
  gemm256<EPI_PREG><<<dim3(16, 16), 512, 0, stream>>>(
      dec_in_bf, 2048, dec_in_bf, 2048, 2048, Wctx_bf, 2048, 2048,
      dbias_p, nullptr, nullptr, pg_bf, nullptr, 0);

  // 5) dec LSTM on the 256^2 pipelined engine (h kept per step when big) + out GEMM
  for (int n = 0; n < 16; n++) {
    bf16* hcur = h_all + (size_t)(big ? n : (n & 1)) * slab;
    const bf16* hprev = (n == 0) ? dec_in_bf
                                 : (h_all + (size_t)(big ? (n - 1) : ((n - 1) & 1)) * slab);
    const int ldprev = (n == 0) ? 2048 : 1024;
    gemm256<EPI_LSTM><<<dim3(16, 16), 512, 0, stream>>>(
        tok_bf + (size_t)n * 2097152, 512, hprev, ldprev, 512,
        Wcat_bf, 1536, 1536,
        nullptr, pg_bf, c_dec, hcur, nullptr, 0);
    if (!big) {
      gemm256<EPI_OUT><<<dim3(2, 16), 512, 0, stream>>>(
          hcur, 1024, hcur, 1024, 1024, outW_bf, 1024, 1024,
          out_b, nullptr, nullptr, nullptr, out, n);
    }
  }
  if (big) {
    // batched out GEMM over all 16 steps: M=65536, N=512, K=1024 on 256^2 engine
    gemm256<EPI_OUT><<<dim3(2, 256), 512, 0, stream>>>(
        h_all, 1024, h_all, 1024, 1024, outW_bf, 1024, 1024,
        out_b, nullptr, nullptr, nullptr, out, -1);
  }
}